// Round 6
// baseline (176.348 us; speedup 1.0000x reference)
//
#include <hip/hip_runtime.h>
#include <math.h>

#define EPSF 1e-4f
#define NBLK 512

static __device__ __forceinline__ float sigmoid_fast(float x) {
    float e = __expf(-x);
    float p = __builtin_amdgcn_rcpf(1.0f + e);
    return fminf(fmaxf(p, EPSF), 1.0f - EPSF);
}
static __device__ __forceinline__ float sigmoid_precise(float x) {
    float p = 1.0f / (1.0f + expf(-x));
    return fminf(fmaxf(p, EPSF), 1.0f - EPSF);
}
static __device__ __forceinline__ float softplus(float x) {
    return fmaxf(x, 0.0f) + log1pf(expf(-fabsf(x)));
}
static __device__ __forceinline__ float4 fmax4(float4 a, float4 b) {
    float4 r;
    r.x = fmaxf(a.x, b.x); r.y = fmaxf(a.y, b.y);
    r.z = fmaxf(a.z, b.z); r.w = fmaxf(a.w, b.w);
    return r;
}

// 3-wide w-window max of a quad from LDS; w-neighbors via lane shuffles.
// Group-edge lanes (w0==0 / WG-1) are true tensor edges => -inf.
template <int WG, int Wc>
static __device__ __forceinline__ float4 wmax_row(const float* pm, int row, int w0) {
    const float4 v = *(const float4*)(pm + (size_t)row * Wc + 4 * w0);
    float lft = __shfl_up(v.w, 1);
    float rgt = __shfl_down(v.x, 1);
    lft = (w0 == 0) ? -INFINITY : lft;
    rgt = (w0 == WG - 1) ? -INFINITY : rgt;
    float4 r;
    r.x = fmaxf(fmaxf(lft, v.x), v.y);
    r.y = fmaxf(fmaxf(v.x, v.y), v.z);
    r.z = fmaxf(fmaxf(v.y, v.z), v.w);
    r.w = fmaxf(fmaxf(v.z, v.w), rgt);
    return r;
}
template <int WG, int Wc>
static __device__ __forceinline__ float4 hfold(const float* pm, int row0, int w0) {
    return fmax4(fmax4(wmax_row<WG, Wc>(pm, row0, w0), wmax_row<WG, Wc>(pm, row0 + 1, w0)),
                 wmax_row<WG, Wc>(pm, row0 + 2, w0));
}

template <int Wc, int TD, int TH, int D, int H>
static __device__ __forceinline__ void tile_decode(
    int tileIdx, int& d0, int& h0, const float*& lg, const float*& gtb,
    const float* logits, const float* gtprob) {
    constexpr int NH = H / TH, ND = D / TD;
    int ht = tileIdx % NH;
    int dt = (tileIdx / NH) % ND;
    int ab = tileIdx / (NH * ND);
    int a = ab & 1, b = ab >> 1;
    h0 = ht * TH; d0 = dt * TD;
    size_t HW = (size_t)H * Wc, vol = (size_t)D * HW;
    lg = logits + ((size_t)b * 8 + a) * vol;   // channel = cls*2 + a
    gtb = gtprob + ((size_t)b * 2 + a) * vol;
}

// Issue all staging loads for a tile into registers (clamped => unconditional).
template <int Wc, int TD, int TH, int D, int H, int NPASS>
static __device__ __forceinline__ void fill_issue(
    const float* lg, int d0, int h0, int tid, float4* pay, bool* pinb) {
    constexpr int WG = Wc / 4, NROWH = TH + 2, NROW = (TD + 2) * NROWH, RPP = 512 / WG;
    const size_t HW = (size_t)H * Wc, cs = 2 * (size_t)D * HW;
    const int w0 = tid % WG, rg = tid / WG;
#pragma unroll
    for (int ps = 0; ps < NPASS; ps++) {
        int r = rg + ps * RPP;
        int rc = r < NROW ? r : NROW - 1;
        int rd = rc / NROWH, rh = rc - rd * NROWH;
        int d = d0 + rd - 1, h = h0 + rh - 1;
        pinb[ps] = ((unsigned)d < (unsigned)D) & ((unsigned)h < (unsigned)H) & (r < NROW);
        int dc = d < 0 ? 0 : (d >= D ? D - 1 : d);
        int hc = h < 0 ? 0 : (h >= H ? H - 1 : h);
        const float* p = lg + (size_t)dc * HW + (size_t)hc * Wc + 4 * w0;
        pay[ps * 4 + 0] = *(const float4*)(p);
        pay[ps * 4 + 1] = *(const float4*)(p + cs);
        pay[ps * 4 + 2] = *(const float4*)(p + 2 * cs);
        pay[ps * 4 + 3] = *(const float4*)(p + 3 * cs);
    }
}

// Reduce 4-class payload to raw max and store to LDS (no transcendentals).
template <int Wc, int TD, int TH, int NPASS>
static __device__ __forceinline__ void fill_write(
    float* buf, int tid, const float4* pay, const bool* pinb) {
    constexpr int WG = Wc / 4, NROWH = TH + 2, NROW = (TD + 2) * NROWH, RPP = 512 / WG;
    const int w0 = tid % WG, rg = tid / WG;
#pragma unroll
    for (int ps = 0; ps < NPASS; ps++) {
        int r = rg + ps * RPP;
        float4 v = fmax4(fmax4(pay[ps * 4 + 0], pay[ps * 4 + 1]),
                         fmax4(pay[ps * 4 + 2], pay[ps * 4 + 3]));
        if (!pinb[ps]) v = make_float4(-INFINITY, -INFINITY, -INFINITY, -INFINITY);
        if (r < NROW) *(float4*)(buf + (size_t)r * Wc + 4 * w0) = v;
    }
}

template <int Wc, int TD, int TH, int D, int H, int CPT>
static __device__ __forceinline__ void gt_issue(
    const float* gtb, int d0, int h0, int tid, float4* gq) {
    constexpr int WG = Wc / 4, RPP = 512 / WG, NCELL = TD * TH;
    const size_t HW = (size_t)H * Wc;
    const int w0 = tid % WG, rg = tid / WG;
#pragma unroll
    for (int k = 0; k < CPT; k++) {
        int cidx = rg + k * RPP;
        int ci = cidx < NCELL ? cidx : 0;
        int dd = ci / TH, hh = ci - dd * TH;
        gq[k] = *(const float4*)(gtb + (size_t)(d0 + dd) * HW + (size_t)(h0 + hh) * Wc + 4 * w0);
    }
}

// Raw-domain selection; sigmoid/log only on selected (~3.7%) elements.
static __device__ __forceinline__ void neg_accum(
    float g, float mx, float pc, double& lsum, double& csum) {
    if (g == -1.0f && mx == pc) {
        float p = sigmoid_fast(pc);
        if (p > EPSF) {
            lsum += (double)(-__logf(1.0f - p) * p);
            csum += (double)p;
        }
    }
}

// L0 compute: each thread owns cells (dd,hh) and (dd+2,hh); slab dd+2 hfold shared.
template <int Wc, int TH>
static __device__ __forceinline__ void compute_pair(
    const float* buf, int tid, const float4* gq, double& ls, double& cs) {
    constexpr int WG = Wc / 4, NROWH = TH + 2;
    const int w0 = tid % WG, rg = tid / WG;   // rg in [0,16)
    const int dd = rg >> 3, hh = rg & 7;
    float4 f0 = hfold<WG, Wc>(buf, (dd + 0) * NROWH + hh, w0);
    float4 f1 = hfold<WG, Wc>(buf, (dd + 1) * NROWH + hh, w0);
    float4 f2 = hfold<WG, Wc>(buf, (dd + 2) * NROWH + hh, w0);
    float4 f3 = hfold<WG, Wc>(buf, (dd + 3) * NROWH + hh, w0);
    float4 f4 = hfold<WG, Wc>(buf, (dd + 4) * NROWH + hh, w0);
    float4 mx0 = fmax4(fmax4(f0, f1), f2);
    float4 mx1 = fmax4(fmax4(f2, f3), f4);
    float4 pc0 = *(const float4*)(buf + (size_t)((dd + 1) * NROWH + hh + 1) * Wc + 4 * w0);
    float4 pc1 = *(const float4*)(buf + (size_t)((dd + 3) * NROWH + hh + 1) * Wc + 4 * w0);
    neg_accum(gq[0].x, mx0.x, pc0.x, ls, cs);
    neg_accum(gq[0].y, mx0.y, pc0.y, ls, cs);
    neg_accum(gq[0].z, mx0.z, pc0.z, ls, cs);
    neg_accum(gq[0].w, mx0.w, pc0.w, ls, cs);
    neg_accum(gq[1].x, mx1.x, pc1.x, ls, cs);
    neg_accum(gq[1].y, mx1.y, pc1.y, ls, cs);
    neg_accum(gq[1].z, mx1.z, pc1.z, ls, cs);
    neg_accum(gq[1].w, mx1.w, pc1.w, ls, cs);
}

// L1 compute: one cell per thread-group (upper half idle, wave-uniform).
template <int Wc, int TD, int TH>
static __device__ __forceinline__ void compute_single(
    const float* buf, int tid, const float4* gq, double& ls, double& cs) {
    constexpr int WG = Wc / 4, NROWH = TH + 2, NCELL = TD * TH;
    const int w0 = tid % WG, rg = tid / WG;
    if (rg < NCELL) {
        int dd = rg / TH, hh = rg - dd * TH;
        float4 f0 = hfold<WG, Wc>(buf, (dd + 0) * NROWH + hh, w0);
        float4 f1 = hfold<WG, Wc>(buf, (dd + 1) * NROWH + hh, w0);
        float4 f2 = hfold<WG, Wc>(buf, (dd + 2) * NROWH + hh, w0);
        float4 mx = fmax4(fmax4(f0, f1), f2);
        float4 pc = *(const float4*)(buf + (size_t)((dd + 1) * NROWH + hh + 1) * Wc + 4 * w0);
        neg_accum(gq[0].x, mx.x, pc.x, ls, cs);
        neg_accum(gq[0].y, mx.y, pc.y, ls, cs);
        neg_accum(gq[0].z, mx.z, pc.z, ls, cs);
        neg_accum(gq[0].w, mx.w, pc.w, ls, cs);
    }
}

// gacc: 6 doubles [loss_pos, loss_neg, loss_other, count_pos, count_neg, count_other]
__global__ __launch_bounds__(512, 4) void fused_kernel(
    const float* __restrict__ lg0, const float* __restrict__ gt0, const int* __restrict__ c0,
    const float* __restrict__ lg1, const float* __restrict__ gt1, const int* __restrict__ c1,
    const float* __restrict__ wcls, double* __restrict__ gacc) {
    __shared__ float buf0[60 * 128];   // L0 tile: 60 rows x 128 (30 KB)
    __shared__ float buf1[60 * 128];
    __shared__ double spart[48];
    __shared__ unsigned present[4];
    const int tid = threadIdx.x;
    const int bid = blockIdx.x;
    double v0 = 0, v1 = 0, v2 = 0, v3 = 0, v4 = 0, v5 = 0;

    if (bid == 0) {
        // ---- pos path (both levels), 128 active threads ----
        if (tid < 4) present[tid] = 0u;
        __syncthreads();
        int lvl = (tid >> 6) & 1, tt = tid & 63;
        int b = tt >> 5, k = tt & 31;
        const float* lg = lvl ? lg1 : lg0;
        const float* gt = lvl ? gt1 : gt0;
        const int* cd = lvl ? c1 : c0;
        int D = lvl ? 32 : 64, H = lvl ? 64 : 128, Wd = lvl ? 64 : 128;
        int a = 0, d = 0, h = 0, w = 0, cls = 0;
        bool valid = false;
        size_t vol = (size_t)D * H * Wd, off = 0;
        if (tid < 128) {
            const int* c = cd + ((size_t)b * 32 + k) * 4;
            a = c[0]; d = c[1]; h = c[2]; w = c[3];
            valid = a > -1;
            if (!valid) { a = 0; d = 0; h = 0; w = 0; }
            off = ((size_t)d * H + h) * (size_t)Wd + w;
            float gval = gt[((size_t)b * 2 + a) * vol + off];
            cls = (int)gval - 1;
            cls = cls < 0 ? 0 : (cls > 3 ? 3 : cls);
            if (valid) atomicOr(&present[lvl * 2 + b], 1u << cls);
        }
        __syncthreads();
        if (tid < 128) {
            unsigned pmask = present[lvl * 2 + b];
            float vm = valid ? 1.0f : 0.0f;
            const float* lgb = lg + (size_t)b * 8 * vol;
            size_t aoff = (size_t)a * vol + off;
            float l_t = lgb[(size_t)cls * 2 * vol + aoff];
            float p_t = sigmoid_precise(l_t);
            float w_pos = (1.0f - p_t) * wcls[cls] * vm;
            float loss_pos = softplus(-l_t) * w_pos;  // -log_sigmoid(l_t)
            float ptg = (p_t > 0.5f) ? 1.0f : 0.0f;
            float lo = 0.0f, co = 0.0f;
#pragma unroll
            for (int cc = 0; cc < 4; cc++) {
                float l_o = lgb[(size_t)cc * 2 * vol + aoff];
                float p_o = sigmoid_precise(l_o);
                float wo = fmaxf(p_o - (p_t - 0.05f), 0.0f) * ((p_o > 0.5f) ? 1.0f : 0.0f) * ptg;
                float pres = ((pmask >> cc) & 1u) ? 1.0f : 0.0f;
                wo *= (1.0f - pres) * vm;
                lo += softplus(l_o) * wo;  // -log_sigmoid(-l_o)
                co += wo;
            }
            v0 = loss_pos; v3 = w_pos; v2 = lo; v5 = co;
        }
        __syncthreads();
    }

    // ---- persistent 3-tile pipeline: L0 tile 2*bid, L0 tile 2*bid+1, L1 tile bid ----
    // prologue: stage tile A into buf0
    int d0a, h0a; const float *lgA, *gtA;
    tile_decode<128, 4, 8, 64, 128>(2 * bid, d0a, h0a, lgA, gtA, lg0, gt0);
    float4 payA[16]; bool inbA[4]; float4 gqA[2];
    fill_issue<128, 4, 8, 64, 128, 4>(lgA, d0a, h0a, tid, payA, inbA);
    gt_issue<128, 4, 8, 64, 128, 2>(gtA, d0a, h0a, tid, gqA);
    fill_write<128, 4, 8, 4>(buf0, tid, payA, inbA);
    __syncthreads();

    // iter 0: stage tile B while computing tile A
    int d0b, h0b; const float *lgB, *gtB;
    tile_decode<128, 4, 8, 64, 128>(2 * bid + 1, d0b, h0b, lgB, gtB, lg0, gt0);
    float4 payB[16]; bool inbB[4]; float4 gqB[2];
    fill_issue<128, 4, 8, 64, 128, 4>(lgB, d0b, h0b, tid, payB, inbB);
    gt_issue<128, 4, 8, 64, 128, 2>(gtB, d0b, h0b, tid, gqB);
    compute_pair<128, 8>(buf0, tid, gqA, v1, v4);
    fill_write<128, 4, 8, 4>(buf1, tid, payB, inbB);
    __syncthreads();

    // iter 1: stage L1 tile while computing tile B
    int d0c, h0c; const float *lgC, *gtC;
    tile_decode<64, 2, 8, 32, 64>(bid, d0c, h0c, lgC, gtC, lg1, gt1);
    float4 payC[8]; bool inbC[2]; float4 gqC[1];
    fill_issue<64, 2, 8, 32, 64, 2>(lgC, d0c, h0c, tid, payC, inbC);
    gt_issue<64, 2, 8, 32, 64, 1>(gtC, d0c, h0c, tid, gqC);
    compute_pair<128, 8>(buf1, tid, gqB, v1, v4);
    fill_write<64, 2, 8, 2>(buf0, tid, payC, inbC);
    __syncthreads();

    // iter 2: compute L1 tile
    compute_single<64, 2, 8>(buf0, tid, gqC, v1, v4);

    // ---- block reduction (double) ----
    for (int o = 32; o > 0; o >>= 1) {
        v1 += __shfl_down(v1, o);
        v4 += __shfl_down(v4, o);
    }
    if (bid == 0) {
        for (int o = 32; o > 0; o >>= 1) {
            v0 += __shfl_down(v0, o); v2 += __shfl_down(v2, o);
            v3 += __shfl_down(v3, o); v5 += __shfl_down(v5, o);
        }
    }
    int wave = tid >> 6, lane = tid & 63;
    if (lane == 0) {
        double* sp = spart + wave * 6;
        sp[0] = v0; sp[1] = v1; sp[2] = v2; sp[3] = v3; sp[4] = v4; sp[5] = v5;
    }
    __syncthreads();
    if (tid == 0) {
        double s1 = 0, s4 = 0;
#pragma unroll
        for (int wv = 0; wv < 8; wv++) { s1 += spart[wv * 6 + 1]; s4 += spart[wv * 6 + 4]; }
        atomicAdd(&gacc[1], s1);
        atomicAdd(&gacc[4], s4);
        if (bid == 0) {
            double s0 = 0, s2 = 0, s3 = 0, s5 = 0;
#pragma unroll
            for (int wv = 0; wv < 8; wv++) {
                s0 += spart[wv * 6 + 0]; s2 += spart[wv * 6 + 2];
                s3 += spart[wv * 6 + 3]; s5 += spart[wv * 6 + 5];
            }
            atomicAdd(&gacc[0], s0); atomicAdd(&gacc[2], s2);
            atomicAdd(&gacc[3], s3); atomicAdd(&gacc[5], s5);
        }
    }
}

__global__ void finalize_kernel(const double* __restrict__ gacc, float* __restrict__ out) {
    int i = threadIdx.x;
    if (i < 6) out[i] = (float)gacc[i];
}

extern "C" void kernel_launch(void* const* d_in, const int* in_sizes, int n_in,
                              void* d_out, int out_size, void* d_ws, size_t ws_size,
                              hipStream_t stream) {
    const float *logits0 = nullptr, *gtprob0 = nullptr, *logits1 = nullptr,
                *gtprob1 = nullptr, *wcls = nullptr;
    const int *coords0 = nullptr, *coords1 = nullptr;
    for (int i = 0; i < n_in; i++) {
        switch (in_sizes[i]) {
            case 16777216: logits0 = (const float*)d_in[i]; break;   // 2*8*64*128*128
            case 4194304:  gtprob0 = (const float*)d_in[i]; break;   // 2*2*64*128*128
            case 2097152:  logits1 = (const float*)d_in[i]; break;   // 2*8*32*64*64
            case 524288:   gtprob1 = (const float*)d_in[i]; break;   // 2*2*32*64*64
            case 4:        wcls    = (const float*)d_in[i]; break;
            case 256:
                if (!coords0) coords0 = (const int*)d_in[i];
                else          coords1 = (const int*)d_in[i];
                break;
        }
    }
    double* gacc = (double*)d_ws;
    hipMemsetAsync(d_ws, 0, 6 * sizeof(double), stream);
    fused_kernel<<<NBLK, 512, 0, stream>>>(logits0, gtprob0, coords0,
                                           logits1, gtprob1, coords1,
                                           wcls, gacc);
    finalize_kernel<<<1, 64, 0, stream>>>(gacc, (float*)d_out);
}

// Round 7
// 139.399 us; speedup vs baseline: 1.2651x; 1.2651x over previous
//
#include <hip/hip_runtime.h>
#include <math.h>

#define EPSF 1e-4f
#define NB_L0 256
#define NB_L1 64
#define NBLK (NB_L0 + NB_L1)

static __device__ __forceinline__ float sigmoid_fast(float x) {
    float e = __expf(-x);
    float p = __builtin_amdgcn_rcpf(1.0f + e);
    return fminf(fmaxf(p, EPSF), 1.0f - EPSF);
}
static __device__ __forceinline__ float sigmoid_precise(float x) {
    float p = 1.0f / (1.0f + expf(-x));
    return fminf(fmaxf(p, EPSF), 1.0f - EPSF);
}
static __device__ __forceinline__ float softplus(float x) {
    return fmaxf(x, 0.0f) + log1pf(expf(-fabsf(x)));
}
static __device__ __forceinline__ float4 fmax4(float4 a, float4 b) {
    float4 r;
    r.x = fmaxf(a.x, b.x); r.y = fmaxf(a.y, b.y);
    r.z = fmaxf(a.z, b.z); r.w = fmaxf(a.w, b.w);
    return r;
}

// 3-wide w-window max of a quad from LDS; w-neighbors via lane shuffles.
// Group-edge lanes (w0==0 / WG-1) are true tensor edges => -inf.
template <int WG, int Wc>
static __device__ __forceinline__ float4 wmax_row(const float* pm, int row, int w0) {
    const float4 v = *(const float4*)(pm + (size_t)row * Wc + 4 * w0);
    float lft = __shfl_up(v.w, 1);
    float rgt = __shfl_down(v.x, 1);
    lft = (w0 == 0) ? -INFINITY : lft;
    rgt = (w0 == WG - 1) ? -INFINITY : rgt;
    float4 r;
    r.x = fmaxf(fmaxf(lft, v.x), v.y);
    r.y = fmaxf(fmaxf(v.x, v.y), v.z);
    r.z = fmaxf(fmaxf(v.y, v.z), v.w);
    r.w = fmaxf(fmaxf(v.z, v.w), rgt);
    return r;
}
template <int WG, int Wc>
static __device__ __forceinline__ float4 hfold(const float* pm, int row0, int w0) {
    return fmax4(fmax4(wmax_row<WG, Wc>(pm, row0, w0), wmax_row<WG, Wc>(pm, row0 + 1, w0)),
                 wmax_row<WG, Wc>(pm, row0 + 2, w0));
}

template <int Wc, int TD, int TH, int D, int H>
static __device__ __forceinline__ void tile_decode(
    int tileIdx, int& d0, int& h0, const float*& lg, const float*& gtb,
    const float* logits, const float* gtprob) {
    constexpr int NH = H / TH, ND = D / TD;
    int ht = tileIdx % NH;
    int dt = (tileIdx / NH) % ND;
    int ab = tileIdx / (NH * ND);
    int a = ab & 1, b = ab >> 1;
    h0 = ht * TH; d0 = dt * TD;
    size_t HW = (size_t)H * Wc, vol = (size_t)D * HW;
    lg = logits + ((size_t)b * 8 + a) * vol;   // channel = cls*2 + a
    gtb = gtprob + ((size_t)b * 2 + a) * vol;
}

// Issue all staging loads for a tile into registers (clamped => unconditional).
template <int Wc, int TD, int TH, int D, int H, int NPASS>
static __device__ __forceinline__ void fill_issue(
    const float* lg, int d0, int h0, int tid, float4* pay, bool* pinb) {
    constexpr int WG = Wc / 4, NROWH = TH + 2, NROW = (TD + 2) * NROWH, RPP = 512 / WG;
    const size_t HW = (size_t)H * Wc, cs = 2 * (size_t)D * HW;
    const int w0 = tid % WG, rg = tid / WG;
#pragma unroll
    for (int ps = 0; ps < NPASS; ps++) {
        int r = rg + ps * RPP;
        int rc = r < NROW ? r : NROW - 1;
        int rd = rc / NROWH, rh = rc - rd * NROWH;
        int d = d0 + rd - 1, h = h0 + rh - 1;
        pinb[ps] = ((unsigned)d < (unsigned)D) & ((unsigned)h < (unsigned)H) & (r < NROW);
        int dc = d < 0 ? 0 : (d >= D ? D - 1 : d);
        int hc = h < 0 ? 0 : (h >= H ? H - 1 : h);
        const float* p = lg + (size_t)dc * HW + (size_t)hc * Wc + 4 * w0;
        pay[ps * 4 + 0] = *(const float4*)(p);
        pay[ps * 4 + 1] = *(const float4*)(p + cs);
        pay[ps * 4 + 2] = *(const float4*)(p + 2 * cs);
        pay[ps * 4 + 3] = *(const float4*)(p + 3 * cs);
    }
}

// Reduce 4-class payload to raw max and store to LDS (no transcendentals).
template <int Wc, int TD, int TH, int NPASS>
static __device__ __forceinline__ void fill_write(
    float* buf, int tid, const float4* pay, const bool* pinb) {
    constexpr int WG = Wc / 4, NROWH = TH + 2, NROW = (TD + 2) * NROWH, RPP = 512 / WG;
    const int w0 = tid % WG, rg = tid / WG;
#pragma unroll
    for (int ps = 0; ps < NPASS; ps++) {
        int r = rg + ps * RPP;
        float4 v = fmax4(fmax4(pay[ps * 4 + 0], pay[ps * 4 + 1]),
                         fmax4(pay[ps * 4 + 2], pay[ps * 4 + 3]));
        if (!pinb[ps]) v = make_float4(-INFINITY, -INFINITY, -INFINITY, -INFINITY);
        if (r < NROW) *(float4*)(buf + (size_t)r * Wc + 4 * w0) = v;
    }
}

template <int Wc, int TD, int TH, int D, int H, int CPT>
static __device__ __forceinline__ void gt_issue(
    const float* gtb, int d0, int h0, int tid, float4* gq) {
    constexpr int WG = Wc / 4, RPP = 512 / WG, NCELL = TD * TH;
    const size_t HW = (size_t)H * Wc;
    const int w0 = tid % WG, rg = tid / WG;
#pragma unroll
    for (int k = 0; k < CPT; k++) {
        int cidx = rg + k * RPP;
        int ci = cidx < NCELL ? cidx : 0;
        int dd = ci / TH, hh = ci - dd * TH;
        gq[k] = *(const float4*)(gtb + (size_t)(d0 + dd) * HW + (size_t)(h0 + hh) * Wc + 4 * w0);
    }
}

// Raw-domain selection; sigmoid/log only on selected (~4%) elements.
static __device__ __forceinline__ void neg_accum(
    float g, float mx, float pc, double& lsum, double& csum) {
    if (g == -1.0f && mx == pc) {
        float p = sigmoid_fast(pc);
        if (p > EPSF) {
            lsum += (double)(-__logf(1.0f - p) * p);
            csum += (double)p;
        }
    }
}

// L0 compute: each thread-group owns cells (dd,hh) and (dd+2,hh); slab dd+2 shared.
template <int Wc, int TH>
static __device__ __forceinline__ void compute_pair(
    const float* buf, int tid, const float4* gq, double& ls, double& cs) {
    constexpr int WG = Wc / 4, NROWH = TH + 2;
    const int w0 = tid % WG, rg = tid / WG;   // rg in [0,16)
    const int dd = rg >> 3, hh = rg & 7;
    float4 f0 = hfold<WG, Wc>(buf, (dd + 0) * NROWH + hh, w0);
    float4 f1 = hfold<WG, Wc>(buf, (dd + 1) * NROWH + hh, w0);
    float4 f2 = hfold<WG, Wc>(buf, (dd + 2) * NROWH + hh, w0);
    float4 f3 = hfold<WG, Wc>(buf, (dd + 3) * NROWH + hh, w0);
    float4 f4 = hfold<WG, Wc>(buf, (dd + 4) * NROWH + hh, w0);
    float4 mx0 = fmax4(fmax4(f0, f1), f2);
    float4 mx1 = fmax4(fmax4(f2, f3), f4);
    float4 pc0 = *(const float4*)(buf + (size_t)((dd + 1) * NROWH + hh + 1) * Wc + 4 * w0);
    float4 pc1 = *(const float4*)(buf + (size_t)((dd + 3) * NROWH + hh + 1) * Wc + 4 * w0);
    neg_accum(gq[0].x, mx0.x, pc0.x, ls, cs);
    neg_accum(gq[0].y, mx0.y, pc0.y, ls, cs);
    neg_accum(gq[0].z, mx0.z, pc0.z, ls, cs);
    neg_accum(gq[0].w, mx0.w, pc0.w, ls, cs);
    neg_accum(gq[1].x, mx1.x, pc1.x, ls, cs);
    neg_accum(gq[1].y, mx1.y, pc1.y, ls, cs);
    neg_accum(gq[1].z, mx1.z, pc1.z, ls, cs);
    neg_accum(gq[1].w, mx1.w, pc1.w, ls, cs);
}

// L1 compute: cells rg and rg+32 (TD=8 x TH=8 = 64 cells, 32 groups).
template <int Wc, int TD, int TH>
static __device__ __forceinline__ void compute_l1(
    const float* buf, int tid, const float4* gq, double& ls, double& cs) {
    constexpr int WG = Wc / 4, NROWH = TH + 2, RPP = 512 / WG;
    const int w0 = tid % WG, rg = tid / WG;
#pragma unroll
    for (int k = 0; k < 2; k++) {
        int c = rg + k * RPP;
        int dd = c / TH, hh = c - dd * TH;
        float4 f0 = hfold<WG, Wc>(buf, (dd + 0) * NROWH + hh, w0);
        float4 f1 = hfold<WG, Wc>(buf, (dd + 1) * NROWH + hh, w0);
        float4 f2 = hfold<WG, Wc>(buf, (dd + 2) * NROWH + hh, w0);
        float4 mx = fmax4(fmax4(f0, f1), f2);
        float4 pc = *(const float4*)(buf + (size_t)((dd + 1) * NROWH + hh + 1) * Wc + 4 * w0);
        neg_accum(gq[k].x, mx.x, pc.x, ls, cs);
        neg_accum(gq[k].y, mx.y, pc.y, ls, cs);
        neg_accum(gq[k].z, mx.z, pc.z, ls, cs);
        neg_accum(gq[k].w, mx.w, pc.w, ls, cs);
    }
}

// gacc: 6 doubles [loss_pos, loss_neg, loss_other, count_pos, count_neg, count_other]
__global__ __launch_bounds__(512, 2) void fused_kernel(
    const float* __restrict__ lg0, const float* __restrict__ gt0, const int* __restrict__ c0,
    const float* __restrict__ lg1, const float* __restrict__ gt1, const int* __restrict__ c1,
    const float* __restrict__ wcls, double* __restrict__ gacc) {
    __shared__ float buf0[60 * 128];   // 30 KB; L1 tiles (100x64) also fit
    __shared__ float buf1[60 * 128];
    __shared__ double spart[48];
    __shared__ unsigned present[4];
    const int tid = threadIdx.x;
    const int bid = blockIdx.x;
    double v0 = 0, v1 = 0, v2 = 0, v3 = 0, v4 = 0, v5 = 0;

    float4 pay[16]; bool inb[4];
    float4 gqA[2], gqB[2];

    if (bid < NB_L0) {
        // ---- L0: 4 consecutive-ht tiles, double-buffered, issue-early ----
        const int t0 = bid * 4;
        int d0, h0; const float *lg, *gtb;
        tile_decode<128, 4, 8, 64, 128>(t0, d0, h0, lg, gtb, lg0, gt0);
        fill_issue<128, 4, 8, 64, 128, 4>(lg, d0, h0, tid, pay, inb);
        gt_issue<128, 4, 8, 64, 128, 2>(gtb, d0, h0, tid, gqA);
        fill_write<128, 4, 8, 4>(buf0, tid, pay, inb);
        __syncthreads();
#pragma unroll
        for (int t = 0; t < 4; t++) {
            float* cur = (t & 1) ? buf1 : buf0;
            float* nxt = (t & 1) ? buf0 : buf1;
            if (t < 3) {
                tile_decode<128, 4, 8, 64, 128>(t0 + t + 1, d0, h0, lg, gtb, lg0, gt0);
                fill_issue<128, 4, 8, 64, 128, 4>(lg, d0, h0, tid, pay, inb);   // loads fly...
                gt_issue<128, 4, 8, 64, 128, 2>(gtb, d0, h0, tid, (t & 1) ? gqA : gqB);
            }
            compute_pair<128, 8>(cur, tid, (t & 1) ? gqB : gqA, v1, v4);        // ...under LDS compute
            if (t < 3) fill_write<128, 4, 8, 4>(nxt, tid, pay, inb);
            __syncthreads();
        }
    } else {
        if (bid == NB_L0) {
            // ---- pos path (both levels), 128 active threads ----
            if (tid < 4) present[tid] = 0u;
            __syncthreads();
            int lvl = (tid >> 6) & 1, tt = tid & 63;
            int b = tt >> 5, k = tt & 31;
            const float* lg = lvl ? lg1 : lg0;
            const float* gt = lvl ? gt1 : gt0;
            const int* cd = lvl ? c1 : c0;
            int D = lvl ? 32 : 64, H = lvl ? 64 : 128, Wd = lvl ? 64 : 128;
            int a = 0, d = 0, h = 0, w = 0, cls = 0;
            bool valid = false;
            size_t vol = (size_t)D * H * Wd, off = 0;
            if (tid < 128) {
                const int* c = cd + ((size_t)b * 32 + k) * 4;
                a = c[0]; d = c[1]; h = c[2]; w = c[3];
                valid = a > -1;
                if (!valid) { a = 0; d = 0; h = 0; w = 0; }
                off = ((size_t)d * H + h) * (size_t)Wd + w;
                float gval = gt[((size_t)b * 2 + a) * vol + off];
                cls = (int)gval - 1;
                cls = cls < 0 ? 0 : (cls > 3 ? 3 : cls);
                if (valid) atomicOr(&present[lvl * 2 + b], 1u << cls);
            }
            __syncthreads();
            if (tid < 128) {
                unsigned pmask = present[lvl * 2 + b];
                float vm = valid ? 1.0f : 0.0f;
                const float* lgb = lg + (size_t)b * 8 * vol;
                size_t aoff = (size_t)a * vol + off;
                float l_t = lgb[(size_t)cls * 2 * vol + aoff];
                float p_t = sigmoid_precise(l_t);
                float w_pos = (1.0f - p_t) * wcls[cls] * vm;
                float loss_pos = softplus(-l_t) * w_pos;  // -log_sigmoid(l_t)
                float ptg = (p_t > 0.5f) ? 1.0f : 0.0f;
                float lo = 0.0f, co = 0.0f;
#pragma unroll
                for (int cc = 0; cc < 4; cc++) {
                    float l_o = lgb[(size_t)cc * 2 * vol + aoff];
                    float p_o = sigmoid_precise(l_o);
                    float wo = fmaxf(p_o - (p_t - 0.05f), 0.0f) * ((p_o > 0.5f) ? 1.0f : 0.0f) * ptg;
                    float pres = ((pmask >> cc) & 1u) ? 1.0f : 0.0f;
                    wo *= (1.0f - pres) * vm;
                    lo += softplus(l_o) * wo;  // -log_sigmoid(-l_o)
                    co += wo;
                }
                v0 = loss_pos; v3 = w_pos; v2 = lo; v5 = co;
            }
            __syncthreads();
        }
        // ---- L1: 2 consecutive-ht tiles (8d x 8h x 64w), double-buffered ----
        const int t0 = (bid - NB_L0) * 2;
        int d0, h0; const float *lg, *gtb;
        tile_decode<64, 8, 8, 32, 64>(t0, d0, h0, lg, gtb, lg1, gt1);
        fill_issue<64, 8, 8, 32, 64, 4>(lg, d0, h0, tid, pay, inb);
        gt_issue<64, 8, 8, 32, 64, 2>(gtb, d0, h0, tid, gqA);
        fill_write<64, 8, 8, 4>(buf0, tid, pay, inb);
        __syncthreads();
#pragma unroll
        for (int t = 0; t < 2; t++) {
            float* cur = (t & 1) ? buf1 : buf0;
            float* nxt = (t & 1) ? buf0 : buf1;
            if (t < 1) {
                tile_decode<64, 8, 8, 32, 64>(t0 + 1, d0, h0, lg, gtb, lg1, gt1);
                fill_issue<64, 8, 8, 32, 64, 4>(lg, d0, h0, tid, pay, inb);
                gt_issue<64, 8, 8, 32, 64, 2>(gtb, d0, h0, tid, gqB);
            }
            compute_l1<64, 8, 8>(cur, tid, (t & 1) ? gqB : gqA, v1, v4);
            if (t < 1) fill_write<64, 8, 8, 4>(nxt, tid, pay, inb);
            __syncthreads();
        }
    }

    // ---- block reduction (double) ----
    for (int o = 32; o > 0; o >>= 1) {
        v1 += __shfl_down(v1, o);
        v4 += __shfl_down(v4, o);
    }
    if (bid == NB_L0) {
        for (int o = 32; o > 0; o >>= 1) {
            v0 += __shfl_down(v0, o); v2 += __shfl_down(v2, o);
            v3 += __shfl_down(v3, o); v5 += __shfl_down(v5, o);
        }
    }
    int wave = tid >> 6, lane = tid & 63;
    if (lane == 0) {
        double* sp = spart + wave * 6;
        sp[0] = v0; sp[1] = v1; sp[2] = v2; sp[3] = v3; sp[4] = v4; sp[5] = v5;
    }
    __syncthreads();
    if (tid == 0) {
        double s1 = 0, s4 = 0;
#pragma unroll
        for (int wv = 0; wv < 8; wv++) { s1 += spart[wv * 6 + 1]; s4 += spart[wv * 6 + 4]; }
        atomicAdd(&gacc[1], s1);
        atomicAdd(&gacc[4], s4);
        if (bid == NB_L0) {
            double s0 = 0, s2 = 0, s3 = 0, s5 = 0;
#pragma unroll
            for (int wv = 0; wv < 8; wv++) {
                s0 += spart[wv * 6 + 0]; s2 += spart[wv * 6 + 2];
                s3 += spart[wv * 6 + 3]; s5 += spart[wv * 6 + 5];
            }
            atomicAdd(&gacc[0], s0); atomicAdd(&gacc[2], s2);
            atomicAdd(&gacc[3], s3); atomicAdd(&gacc[5], s5);
        }
    }
}

__global__ void finalize_kernel(const double* __restrict__ gacc, float* __restrict__ out) {
    int i = threadIdx.x;
    if (i < 6) out[i] = (float)gacc[i];
}

extern "C" void kernel_launch(void* const* d_in, const int* in_sizes, int n_in,
                              void* d_out, int out_size, void* d_ws, size_t ws_size,
                              hipStream_t stream) {
    const float *logits0 = nullptr, *gtprob0 = nullptr, *logits1 = nullptr,
                *gtprob1 = nullptr, *wcls = nullptr;
    const int *coords0 = nullptr, *coords1 = nullptr;
    for (int i = 0; i < n_in; i++) {
        switch (in_sizes[i]) {
            case 16777216: logits0 = (const float*)d_in[i]; break;   // 2*8*64*128*128
            case 4194304:  gtprob0 = (const float*)d_in[i]; break;   // 2*2*64*128*128
            case 2097152:  logits1 = (const float*)d_in[i]; break;   // 2*8*32*64*64
            case 524288:   gtprob1 = (const float*)d_in[i]; break;   // 2*2*32*64*64
            case 4:        wcls    = (const float*)d_in[i]; break;
            case 256:
                if (!coords0) coords0 = (const int*)d_in[i];
                else          coords1 = (const int*)d_in[i];
                break;
        }
    }
    double* gacc = (double*)d_ws;
    hipMemsetAsync(d_ws, 0, 6 * sizeof(double), stream);
    fused_kernel<<<NBLK, 512, 0, stream>>>(logits0, gtprob0, coords0,
                                           logits1, gtprob1, coords1,
                                           wcls, gacc);
    finalize_kernel<<<1, 64, 0, stream>>>(gacc, (float*)d_out);
}